// Round 1
// baseline (16307.925 us; speedup 1.0000x reference)
//
#include <hip/hip_runtime.h>
#include <cstdint>
#include <cstddef>

typedef __attribute__((ext_vector_type(8))) short short8;
typedef __attribute__((ext_vector_type(4))) float f32x4;

#define DEV static __device__ __forceinline__

DEV float b2f(unsigned short u){ union{unsigned int i; float f;} v; v.i = ((unsigned int)u)<<16; return v.f; }
DEV unsigned short f2b(float f){
  union{float f; unsigned int i;} v; v.f = f;
  unsigned int u = v.i;
  unsigned int r = (u + 0x7fffu + ((u>>16)&1u)) >> 16;
  return (unsigned short)r;
}
DEV float sigm(float x){ return 1.0f/(1.0f + __expf(-x)); }
DEV float tanhfast(float x){ return 1.0f - 2.0f/(1.0f + __expf(2.0f*x)); }

// ---------------- prep kernels ----------------
__global__ __launch_bounds__(256) void k_cast(const float* __restrict__ s, unsigned short* __restrict__ d, int n){
  int i = blockIdx.x*256 + threadIdx.x;
  if (i < n) d[i] = f2b(s[i]);
}
__global__ __launch_bounds__(256) void k_transpose_enc(const float* __restrict__ enc, unsigned short* __restrict__ encT){
  int i = blockIdx.x*256 + threadIdx.x;   // over 16*512*512, out index [b][h][s]
  if (i >= 16*512*512) return;
  int b = i >> 18, r = i & 262143, h = r >> 9, s = r & 511;
  encT[i] = f2b(enc[(b<<18) + (s<<9) + h]);
}
__global__ __launch_bounds__(256) void k_gather(const int* __restrict__ trg, const float* __restrict__ emb, unsigned short* __restrict__ X){
  int i = blockIdx.x*256 + threadIdx.x;   // over 8192*512, row = t*16+b
  if (i >= 8192*512) return;
  int r = i >> 9, e = i & 511;
  int t = r >> 4, b = r & 15;
  int tok = trg[(b<<9) + t];
  X[i] = f2b(emb[((size_t)tok<<9) + e]);
}
__global__ __launch_bounds__(256) void k_bsum(const float* __restrict__ bi, const float* __restrict__ bh, float* __restrict__ o){
  int i = blockIdx.x*256 + threadIdx.x;
  if (i < 8192) o[i] = bi[i] + bh[i];
}
__global__ __launch_bounds__(256) void k_init(const float* __restrict__ h0, unsigned short* __restrict__ Hst0,
                                              unsigned short* __restrict__ Hst1, int* __restrict__ bar){
  int i = blockIdx.x*256 + threadIdx.x;
  if (i < 128) bar[i] = 0;
  if (i < 16384) {                    // buf0 region: [dir][b][k] ; h0 flat [l*2+dir][b][k]
    Hst0[i] = f2b(h0[i]);             // layer 0: dirs 0,1
    Hst1[i] = f2b(h0[16384 + i]);     // layer 1: dirs 2,3
  }
}
__global__ __launch_bounds__(256) void k_split(const float* __restrict__ S, unsigned short* __restrict__ H,
                                               unsigned short* __restrict__ L, int n){
  int i = blockIdx.x*256 + threadIdx.x;
  if (i >= n) return;
  float f = S[i];
  unsigned short hi = f2b(f);
  H[i] = hi;
  L[i] = f2b(f - b2f(hi));
}
__global__ __launch_bounds__(256) void k_decsplit(const float* __restrict__ HF, unsigned short* __restrict__ DCTX,
                                                  unsigned short* __restrict__ DH, unsigned short* __restrict__ DL){
  int i = blockIdx.x*256 + threadIdx.x;  // 8192*512
  if (i >= 8192*512) return;
  int r = i >> 9, j = i & 511;
  float d = HF[((size_t)r<<10) + j] + HF[((size_t)r<<10) + 512 + j];
  unsigned short hi = f2b(d);
  DCTX[((size_t)r<<10) + j] = hi;   // dec half of FC input
  DH[i] = hi;
  DL[i] = f2b(d - b2f(hi));
}

// ---------------- generic bf16 MFMA GEMM: C = A[M,K] @ W[N,K]^T (+bias) ----------------
// MODE: 0 = store bf16, 1 = store f32 (+bias), 2 = FC epilogue (mask+remap), 3 = f32 +=
template<int MODE>
__global__ __launch_bounds__(256) void k_gemm(
    const unsigned short* __restrict__ A, long lda, long sA,
    const unsigned short* __restrict__ W, long ldw, long sW,
    void* __restrict__ C, long ldc, long sC,
    const float* __restrict__ bias,
    int M, int N, int K,
    const int* __restrict__ tlen)
{
  __shared__ short8 AsV[128*5];   // 128 rows x 32 bf16, padded stride 5x short8 (conflict-spread)
  __shared__ short8 WsV[128*5];
  const int bz = blockIdx.z;
  const unsigned short* Ab = A + (size_t)bz * sA;
  const unsigned short* Wb = W + (size_t)bz * sW;
  const int m0 = blockIdx.x << 7, n0 = blockIdx.y << 7;
  const int tid = threadIdx.x;
  const int wave = tid >> 6, lane = tid & 63;
  const int ln = lane & 15, kq = lane >> 4;
  const int wm = wave >> 1, wn = wave & 1;
  const int ar0 = tid >> 2, ac0 = (tid & 3) << 3;
  const int ar1 = ar0 + 64;
  const short8 z8 = {0,0,0,0,0,0,0,0};

  f32x4 acc[4][4];
  #pragma unroll
  for (int i = 0; i < 4; ++i)
    #pragma unroll
    for (int j = 0; j < 4; ++j) { f32x4 z = {0.f,0.f,0.f,0.f}; acc[i][j] = z; }

  for (int k0 = 0; k0 < K; k0 += 32) {
    short8 a0 = *(const short8*)(Ab + (size_t)(m0+ar0)*lda + k0 + ac0);
    short8 a1 = *(const short8*)(Ab + (size_t)(m0+ar1)*lda + k0 + ac0);
    short8 w0 = z8, w1 = z8;
    if (MODE != 2 || (n0+ar0) < N) w0 = *(const short8*)(Wb + (size_t)(n0+ar0)*ldw + k0 + ac0);
    if (MODE != 2 || (n0+ar1) < N) w1 = *(const short8*)(Wb + (size_t)(n0+ar1)*ldw + k0 + ac0);
    __syncthreads();
    AsV[ar0*5 + (ac0>>3)] = a0;
    AsV[ar1*5 + (ac0>>3)] = a1;
    WsV[ar0*5 + (ac0>>3)] = w0;
    WsV[ar1*5 + (ac0>>3)] = w1;
    __syncthreads();
    short8 af[4], wf[4];
    #pragma unroll
    for (int i = 0; i < 4; ++i) af[i] = AsV[((wm<<6) + (i<<4) + ln)*5 + kq];
    #pragma unroll
    for (int i = 0; i < 4; ++i) wf[i] = WsV[((wn<<6) + (i<<4) + ln)*5 + kq];
    #pragma unroll
    for (int i = 0; i < 4; ++i)
      #pragma unroll
      for (int j = 0; j < 4; ++j)
        acc[i][j] = __builtin_amdgcn_mfma_f32_16x16x32_bf16(af[i], wf[j], acc[i][j], 0, 0, 0);
  }
  #pragma unroll
  for (int j = 0; j < 4; ++j) {
    const int n = n0 + (wn<<6) + (j<<4) + ln;
    float bi = 0.f;
    if (MODE == 0 || MODE == 1) { if (bias) bi = bias[n]; }
    if (MODE == 2) { if (n < N) bi = bias[n]; }
    #pragma unroll
    for (int i = 0; i < 4; ++i) {
      #pragma unroll
      for (int r = 0; r < 4; ++r) {
        const int m = m0 + (wm<<6) + (i<<4) + (kq<<2) + r;
        float v = acc[i][j][r] + bi;
        if (MODE == 0) ((unsigned short*)C)[(size_t)bz*sC + (size_t)m*ldc + n] = f2b(v);
        else if (MODE == 1) ((float*)C)[(size_t)bz*sC + (size_t)m*ldc + n] = v;
        else if (MODE == 3) ((float*)C)[(size_t)bz*sC + (size_t)m*ldc + n] += v;
        else {
          if (n < N) {
            int tt = m >> 4, bb = m & 15;
            ((float*)C)[((size_t)((bb<<9) + tt))*1000 + n] = (tt < tlen[bb]) ? v : 0.0f;
          }
        }
      }
    }
  }
}

// ---------------- persistent LSTM layer (one dir-pair, 512 steps) ----------------
// 64 blocks: dir = bid>>5, j-chunk of 16 per block. Per block: wave q holds its
// 16x512 bf16 W_hh slice in registers; gates via 16 chained MFMAs; fp32 cell update.
__global__ __launch_bounds__(256) void k_lstm(
    const unsigned short* __restrict__ Whh,   // [2][2048][512] bf16 (this layer)
    const unsigned short* __restrict__ Xg,    // [8192][4096] bf16 (x@Wih^T + b_ih + b_hh)
    const float*  __restrict__ c0,            // [2][16][512] f32 (this layer)
    unsigned short* __restrict__ Hst,         // [2 buf][2 dir][16][512] bf16
    unsigned short* __restrict__ Hcat,        // [8192][1024] bf16
    float*  __restrict__ HcatF,               // optional fp32 copy (layer 1 only)
    int* bar)
{
  const int bid = blockIdx.x;
  const int dir = bid >> 5;
  const int j0  = (bid & 31) << 4;
  const int tid = threadIdx.x;
  const int wave = tid >> 6;        // gate q: 0=i 1=f 2=g 3=o
  const int lane = tid & 63;
  const int ln = lane & 15, kq = lane >> 4;

  short8 wfrag[16];
  {
    const unsigned short* wb = Whh + (((size_t)((dir<<11) + (wave<<9) + j0 + ln)) << 9) + (kq<<3);
    #pragma unroll
    for (int ks = 0; ks < 16; ++ks)
      wfrag[ks] = *(const short8*)(wb + (ks<<5));
  }
  const int b_ = tid >> 4, jl = tid & 15;
  float c = c0[((size_t)((dir<<4) + b_) << 9) + j0 + jl];

  __shared__ float gsh[4][16][16];
  int* cnt = bar + (dir<<5);
  int* gen = cnt + 16;

  for (int t = 0; t < 512; ++t) {
    const unsigned short* hb = Hst + ((((t&1)<<1) + dir)<<13) + (ln<<9) + (kq<<3);
    f32x4 acc = {0.f,0.f,0.f,0.f};
    #pragma unroll
    for (int ks = 0; ks < 16; ++ks) {
      short8 af = *(const short8*)(hb + (ks<<5));
      acc = __builtin_amdgcn_mfma_f32_16x16x32_bf16(af, wfrag[ks], acc, 0, 0, 0);
    }
    #pragma unroll
    for (int r = 0; r < 4; ++r)
      gsh[wave][(kq<<2)+r][ln] = acc[r];
    __syncthreads();

    const size_t xr = (((size_t)((t<<4) + b_)) << 12) + (dir<<11) + j0 + jl;
    float gi = gsh[0][b_][jl] + b2f(Xg[xr]);
    float gf = gsh[1][b_][jl] + b2f(Xg[xr + 512]);
    float gg = gsh[2][b_][jl] + b2f(Xg[xr + 1024]);
    float go = gsh[3][b_][jl] + b2f(Xg[xr + 1536]);
    float ii = sigm(gi), ff = sigm(gf);
    float g2 = tanhfast(gg), oo = sigm(go);
    c = ff*c + ii*g2;
    float h = oo * tanhfast(c);
    unsigned short h16 = f2b(h);
    Hst[(((((t+1)&1)<<1) + dir)<<13) + (b_<<9) + j0 + jl] = h16;
    size_t crow = (((size_t)((t<<4) + b_)) << 10) + (dir<<9) + j0 + jl;
    Hcat[crow] = h16;
    if (HcatF) HcatF[crow] = h;

    // per-dir grid barrier (32 blocks), sense-reversing
    __threadfence();
    __syncthreads();
    if (tid == 0) {
      int g0 = __hip_atomic_load(gen, __ATOMIC_RELAXED, __HIP_MEMORY_SCOPE_AGENT);
      int prev = __hip_atomic_fetch_add(cnt, 1, __ATOMIC_ACQ_REL, __HIP_MEMORY_SCOPE_AGENT);
      if (prev == 31) {
        __hip_atomic_store(cnt, 0, __ATOMIC_RELAXED, __HIP_MEMORY_SCOPE_AGENT);
        __hip_atomic_store(gen, g0 + 1, __ATOMIC_RELEASE, __HIP_MEMORY_SCOPE_AGENT);
      } else {
        while (__hip_atomic_load(gen, __ATOMIC_ACQUIRE, __HIP_MEMORY_SCOPE_AGENT) == g0)
          __builtin_amdgcn_s_sleep(1);
      }
    }
    __syncthreads();
    __threadfence();
  }
}

// ---------------- softmax over masked scores -> bf16 attention ----------------
__global__ __launch_bounds__(256) void k_softmax(const float* __restrict__ score, const int* __restrict__ tlen,
                                                 unsigned short* __restrict__ att){
  int row = (blockIdx.x<<2) + (threadIdx.x>>6);   // row = b*512 + t
  int lane = threadIdx.x & 63;
  int b = row >> 9;
  int len = tlen[b];
  const float* sr = score + ((size_t)row<<9);
  float v[8]; float m = -3.0e38f;
  #pragma unroll
  for (int i = 0; i < 8; ++i) {
    int s = (i<<6) + lane;
    float x = sr[s];
    v[i] = (s < len) ? x : -1.0e30f;
    m = fmaxf(m, v[i]);
  }
  #pragma unroll
  for (int off = 32; off; off >>= 1) m = fmaxf(m, __shfl_xor(m, off));
  float sum = 0.f; float p[8];
  #pragma unroll
  for (int i = 0; i < 8; ++i) { p[i] = __expf(v[i] - m); sum += p[i]; }
  #pragma unroll
  for (int off = 32; off; off >>= 1) sum += __shfl_xor(sum, off);
  float inv = 1.0f / sum;
  unsigned short* ar = att + ((size_t)row<<9);
  #pragma unroll
  for (int i = 0; i < 8; ++i) ar[(i<<6) + lane] = f2b(p[i]*inv);
}

// ---------------- host ----------------
extern "C" void kernel_launch(void* const* d_in, const int* in_sizes, int n_in,
                              void* d_out, int out_size, void* d_ws, size_t ws_size,
                              hipStream_t stream) {
  (void)in_sizes; (void)n_in; (void)out_size; (void)ws_size;
  const int*   trg  = (const int*)d_in[0];
  const int*   tlen = (const int*)d_in[1];
  const float* enc  = (const float*)d_in[2];
  const float* h0   = (const float*)d_in[3];
  const float* c0   = (const float*)d_in[4];
  const float* emb  = (const float*)d_in[5];
  const float* wih0 = (const float*)d_in[6];
  const float* wih1 = (const float*)d_in[7];
  const float* whh  = (const float*)d_in[8];
  const float* bih  = (const float*)d_in[9];
  const float* bhh  = (const float*)d_in[10];
  const float* watt = (const float*)d_in[11];
  const float* batt = (const float*)d_in[12];
  const float* wfc  = (const float*)d_in[13];
  const float* bfc  = (const float*)d_in[14];
  float* out = (float*)d_out;

  char* ws = (char*)d_ws;
  size_t off = 0;
  auto alloc = [&](size_t bytes)->char* {
    char* p = ws + off; off += (bytes + 255) & ~(size_t)255; return p;
  };
  int*            BAR   = (int*)           alloc(512);
  unsigned short* XEMB  = (unsigned short*)alloc(8192ll*512*2);
  unsigned short* WI0B  = (unsigned short*)alloc(4096ll*512*2);
  unsigned short* WI1B  = (unsigned short*)alloc(4096ll*1024*2);
  unsigned short* WHHB  = (unsigned short*)alloc(2ll*4096*512*2);
  unsigned short* WFCB  = (unsigned short*)alloc(1000ll*1024*2);
  unsigned short* WATTB = (unsigned short*)alloc(512ll*512*2);
  unsigned short* ENCB  = (unsigned short*)alloc(8192ll*512*2);
  unsigned short* ENCT  = (unsigned short*)alloc(8192ll*512*2);
  float*          BSUM  = (float*)         alloc(8192*4);
  unsigned short* HST0  = (unsigned short*)alloc(32768*2);
  unsigned short* HST1  = (unsigned short*)alloc(32768*2);
  unsigned short* XG    = (unsigned short*)alloc(8192ll*4096*2);
  unsigned short* HCAT  = (unsigned short*)alloc(8192ll*1024*2);
  float*          HCATF = (float*)         alloc(8192ll*1024*4);
  float*          SCORE = (float*)         alloc(8192ll*512*4);   // also used as ENCP f32 staging
  unsigned short* ENCPH = (unsigned short*)alloc(8192ll*512*2);
  unsigned short* ENCPL = (unsigned short*)alloc(8192ll*512*2);
  unsigned short* DECH  = (unsigned short*)alloc(8192ll*512*2);
  unsigned short* DECL  = (unsigned short*)alloc(8192ll*512*2);
  unsigned short* ATT   = (unsigned short*)alloc(8192ll*512*2);
  unsigned short* DCTX  = (unsigned short*)alloc(8192ll*1024*2);

  auto cdiv = [](long a, long b){ return (int)((a + b - 1) / b); };

  // ---- prep ----
  k_cast<<<cdiv(2097152,256),256,0,stream>>>(wih0, WI0B, 2097152);
  k_cast<<<cdiv(4194304,256),256,0,stream>>>(wih1, WI1B, 4194304);
  k_cast<<<cdiv(4194304,256),256,0,stream>>>(whh,  WHHB, 4194304);
  k_cast<<<cdiv(1024000,256),256,0,stream>>>(wfc,  WFCB, 1024000);
  k_cast<<<cdiv(262144,256),256,0,stream>>>(watt, WATTB, 262144);
  k_cast<<<cdiv(4194304,256),256,0,stream>>>(enc,  ENCB, 4194304);
  k_transpose_enc<<<cdiv(4194304,256),256,0,stream>>>(enc, ENCT);
  k_gather<<<cdiv(4194304,256),256,0,stream>>>(trg, emb, XEMB);
  k_bsum<<<cdiv(8192,256),256,0,stream>>>(bih, bhh, BSUM);
  k_init<<<cdiv(32768,256),256,0,stream>>>(h0, HST0, HST1, BAR);

  // ---- enc_proj = enc @ W_att^T + b_att (f32), then hi/lo split ----
  k_gemm<1><<<dim3(64,4,1),256,0,stream>>>(ENCB,512,0, WATTB,512,0, (void*)SCORE,512,0, batt, 8192,512,512, nullptr);
  k_split<<<cdiv(4194304,256),256,0,stream>>>(SCORE, ENCPH, ENCPL, 4194304);

  // ---- X0 = Xemb @ W_ih0^T + (b_ih+b_hh)[0]  -> XG bf16 ----
  k_gemm<0><<<dim3(64,32,1),256,0,stream>>>(XEMB,512,0, WI0B,512,0, (void*)XG,4096,0, BSUM, 8192,4096,512, nullptr);

  // ---- layer 0 recurrence ----
  k_lstm<<<64,256,0,stream>>>(WHHB, XG, c0, HST0, HCAT, nullptr, BAR);

  // ---- X1 = H0cat @ W_ih1^T + (b_ih+b_hh)[1]  -> XG bf16 (reuse) ----
  k_gemm<0><<<dim3(64,32,1),256,0,stream>>>(HCAT,1024,0, WI1B,1024,0, (void*)XG,4096,0, BSUM+4096, 8192,4096,1024, nullptr);

  // ---- layer 1 recurrence (also fp32 H for dec) ----
  k_lstm<<<64,256,0,stream>>>(WHHB + 2097152, XG, c0 + 16384, HST1, HCAT, HCATF, BAR);

  // ---- dec = hf+hb (fp32) -> DCTX[:, :512] bf16, DECH/DECL split ----
  k_decsplit<<<cdiv(4194304,256),256,0,stream>>>(HCATF, DCTX, DECH, DECL);

  // ---- score[b,t,s] = dec . enc_proj  (hi/lo compensated, batched z=b) ----
  k_gemm<1><<<dim3(4,4,16),256,0,stream>>>(DECH,8192,512, ENCPH,512,262144, (void*)SCORE,512,262144, nullptr, 512,512,512, nullptr);
  k_gemm<3><<<dim3(4,4,16),256,0,stream>>>(DECH,8192,512, ENCPL,512,262144, (void*)SCORE,512,262144, nullptr, 512,512,512, nullptr);
  k_gemm<3><<<dim3(4,4,16),256,0,stream>>>(DECL,8192,512, ENCPH,512,262144, (void*)SCORE,512,262144, nullptr, 512,512,512, nullptr);

  // ---- masked softmax -> ATT bf16 ----
  k_softmax<<<2048,256,0,stream>>>(SCORE, tlen, ATT);

  // ---- ctx[b,t,h] = att @ enc  -> DCTX[:, 512:] bf16 (batched) ----
  k_gemm<0><<<dim3(4,4,16),256,0,stream>>>(ATT,512,262144, ENCT,512,262144, (void*)(DCTX+512),16384,1024, nullptr, 512,512,512, nullptr);

  // ---- out = [dec,ctx] @ W_fc^T + b_fc, masked by trg_len ----
  k_gemm<2><<<dim3(64,8,1),256,0,stream>>>(DCTX,1024,0, WFCB,1024,0, (void*)out,1000,0, bfc, 8192,1000,1024, tlen);
}

// Round 2
// 5170.161 us; speedup vs baseline: 3.1542x; 3.1542x over previous
//
#include <hip/hip_runtime.h>
#include <cstdint>
#include <cstddef>

typedef __attribute__((ext_vector_type(8))) short short8;
typedef __attribute__((ext_vector_type(4))) float f32x4;

#define DEV static __device__ __forceinline__

DEV float b2f(unsigned short u){ union{unsigned int i; float f;} v; v.i = ((unsigned int)u)<<16; return v.f; }
DEV unsigned short f2b(float f){
  union{float f; unsigned int i;} v; v.f = f;
  unsigned int u = v.i;
  unsigned int r = (u + 0x7fffu + ((u>>16)&1u)) >> 16;
  return (unsigned short)r;
}
DEV float sigm(float x){ return 1.0f/(1.0f + __expf(-x)); }
DEV float tanhfast(float x){ return 1.0f - 2.0f/(1.0f + __expf(2.0f*x)); }

// ---------------- prep kernels ----------------
__global__ __launch_bounds__(256) void k_cast(const float* __restrict__ s, unsigned short* __restrict__ d, int n){
  int i = blockIdx.x*256 + threadIdx.x;
  if (i < n) d[i] = f2b(s[i]);
}
__global__ __launch_bounds__(256) void k_transpose_enc(const float* __restrict__ enc, unsigned short* __restrict__ encT){
  int i = blockIdx.x*256 + threadIdx.x;   // over 16*512*512, out index [b][h][s]
  if (i >= 16*512*512) return;
  int b = i >> 18, r = i & 262143, h = r >> 9, s = r & 511;
  encT[i] = f2b(enc[(b<<18) + (s<<9) + h]);
}
__global__ __launch_bounds__(256) void k_gather(const int* __restrict__ trg, const float* __restrict__ emb, unsigned short* __restrict__ X){
  int i = blockIdx.x*256 + threadIdx.x;   // over 8192*512, row = t*16+b
  if (i >= 8192*512) return;
  int r = i >> 9, e = i & 511;
  int t = r >> 4, b = r & 15;
  int tok = trg[(b<<9) + t];
  X[i] = f2b(emb[((size_t)tok<<9) + e]);
}
__global__ __launch_bounds__(256) void k_bsum(const float* __restrict__ bi, const float* __restrict__ bh, float* __restrict__ o){
  int i = blockIdx.x*256 + threadIdx.x;
  if (i < 8192) o[i] = bi[i] + bh[i];
}
__global__ __launch_bounds__(256) void k_init(const float* __restrict__ h0, unsigned short* __restrict__ Hst0,
                                              unsigned short* __restrict__ Hst1, int* __restrict__ bar){
  int i = blockIdx.x*256 + threadIdx.x;
  if (i < 256) bar[i] = 0;
  if (i < 16384) {                    // buf0 region: [dir][b][k] ; h0 flat [l*2+dir][b][k]
    Hst0[i] = f2b(h0[i]);             // layer 0: dirs 0,1
    Hst1[i] = f2b(h0[16384 + i]);     // layer 1: dirs 2,3
  }
}
__global__ __launch_bounds__(256) void k_split(const float* __restrict__ S, unsigned short* __restrict__ H,
                                               unsigned short* __restrict__ L, int n){
  int i = blockIdx.x*256 + threadIdx.x;
  if (i >= n) return;
  float f = S[i];
  unsigned short hi = f2b(f);
  H[i] = hi;
  L[i] = f2b(f - b2f(hi));
}
__global__ __launch_bounds__(256) void k_decsplit(const float* __restrict__ HF, unsigned short* __restrict__ DCTX,
                                                  unsigned short* __restrict__ DH, unsigned short* __restrict__ DL){
  int i = blockIdx.x*256 + threadIdx.x;  // 8192*512
  if (i >= 8192*512) return;
  int r = i >> 9, j = i & 511;
  float d = HF[((size_t)r<<10) + j] + HF[((size_t)r<<10) + 512 + j];
  unsigned short hi = f2b(d);
  DCTX[((size_t)r<<10) + j] = hi;   // dec half of FC input
  DH[i] = hi;
  DL[i] = f2b(d - b2f(hi));
}

// ---------------- generic bf16 MFMA GEMM: C = A[M,K] @ W[N,K]^T (+bias) ----------------
// MODE: 0 = store bf16, 1 = store f32 (+bias), 2 = FC epilogue (mask+remap), 3 = f32 +=
template<int MODE>
__global__ __launch_bounds__(256) void k_gemm(
    const unsigned short* __restrict__ A, long lda, long sA,
    const unsigned short* __restrict__ W, long ldw, long sW,
    void* __restrict__ C, long ldc, long sC,
    const float* __restrict__ bias,
    int M, int N, int K,
    const int* __restrict__ tlen)
{
  __shared__ short8 AsV[128*5];   // 128 rows x 32 bf16, padded stride 5x short8 (conflict-spread)
  __shared__ short8 WsV[128*5];
  const int bz = blockIdx.z;
  const unsigned short* Ab = A + (size_t)bz * sA;
  const unsigned short* Wb = W + (size_t)bz * sW;
  const int m0 = blockIdx.x << 7, n0 = blockIdx.y << 7;
  const int tid = threadIdx.x;
  const int wave = tid >> 6, lane = tid & 63;
  const int ln = lane & 15, kq = lane >> 4;
  const int wm = wave >> 1, wn = wave & 1;
  const int ar0 = tid >> 2, ac0 = (tid & 3) << 3;
  const int ar1 = ar0 + 64;
  const short8 z8 = {0,0,0,0,0,0,0,0};

  f32x4 acc[4][4];
  #pragma unroll
  for (int i = 0; i < 4; ++i)
    #pragma unroll
    for (int j = 0; j < 4; ++j) { f32x4 z = {0.f,0.f,0.f,0.f}; acc[i][j] = z; }

  for (int k0 = 0; k0 < K; k0 += 32) {
    short8 a0 = *(const short8*)(Ab + (size_t)(m0+ar0)*lda + k0 + ac0);
    short8 a1 = *(const short8*)(Ab + (size_t)(m0+ar1)*lda + k0 + ac0);
    short8 w0 = z8, w1 = z8;
    if (MODE != 2 || (n0+ar0) < N) w0 = *(const short8*)(Wb + (size_t)(n0+ar0)*ldw + k0 + ac0);
    if (MODE != 2 || (n0+ar1) < N) w1 = *(const short8*)(Wb + (size_t)(n0+ar1)*ldw + k0 + ac0);
    __syncthreads();
    AsV[ar0*5 + (ac0>>3)] = a0;
    AsV[ar1*5 + (ac0>>3)] = a1;
    WsV[ar0*5 + (ac0>>3)] = w0;
    WsV[ar1*5 + (ac0>>3)] = w1;
    __syncthreads();
    short8 af[4], wf[4];
    #pragma unroll
    for (int i = 0; i < 4; ++i) af[i] = AsV[((wm<<6) + (i<<4) + ln)*5 + kq];
    #pragma unroll
    for (int i = 0; i < 4; ++i) wf[i] = WsV[((wn<<6) + (i<<4) + ln)*5 + kq];
    #pragma unroll
    for (int i = 0; i < 4; ++i)
      #pragma unroll
      for (int j = 0; j < 4; ++j)
        acc[i][j] = __builtin_amdgcn_mfma_f32_16x16x32_bf16(af[i], wf[j], acc[i][j], 0, 0, 0);
  }
  #pragma unroll
  for (int j = 0; j < 4; ++j) {
    const int n = n0 + (wn<<6) + (j<<4) + ln;
    float bi = 0.f;
    if (MODE == 0 || MODE == 1) { if (bias) bi = bias[n]; }
    if (MODE == 2) { if (n < N) bi = bias[n]; }
    #pragma unroll
    for (int i = 0; i < 4; ++i) {
      #pragma unroll
      for (int r = 0; r < 4; ++r) {
        const int m = m0 + (wm<<6) + (i<<4) + (kq<<2) + r;
        float v = acc[i][j][r] + bi;
        if (MODE == 0) ((unsigned short*)C)[(size_t)bz*sC + (size_t)m*ldc + n] = f2b(v);
        else if (MODE == 1) ((float*)C)[(size_t)bz*sC + (size_t)m*ldc + n] = v;
        else if (MODE == 3) ((float*)C)[(size_t)bz*sC + (size_t)m*ldc + n] += v;
        else {
          if (n < N) {
            int tt = m >> 4, bb = m & 15;
            ((float*)C)[((size_t)((bb<<9) + tt))*1000 + n] = (tt < tlen[bb]) ? v : 0.0f;
          }
        }
      }
    }
  }
}

// ---------------- persistent LSTM layer (one dir-pair, 512 steps) ----------------
// 64 blocks: dir = bid>>5, j-chunk of 16 per block. Per block: wave q holds its
// 16x512 bf16 W_hh slice in registers; gates via 16 MFMAs (2 chains); fp32 cell update.
// Barrier: monotonic per-dir counter; arrive with ACQ_REL fetch_add (the release
// wbl2 publishes this block's h stores), poll with RELAXED loads (sc1, no L2
// invalidate per poll), then ONE acquire fence. No threadfence, no gen/reset.
__global__ __launch_bounds__(256) void k_lstm(
    const unsigned short* __restrict__ Whh,   // [2][2048][512] bf16 (this layer)
    const unsigned short* __restrict__ Xg,    // [8192][4096] bf16 (x@Wih^T + b_ih + b_hh)
    const float*  __restrict__ c0,            // [2][16][512] f32 (this layer)
    unsigned short* __restrict__ Hst,         // [2 buf][2 dir][16][512] bf16
    unsigned short* __restrict__ Hcat,        // [8192][1024] bf16
    float*  __restrict__ HcatF,               // optional fp32 copy (layer 1 only)
    int* bar)
{
  const int bid = blockIdx.x;
  const int dir = bid >> 5;
  const int j0  = (bid & 31) << 4;
  const int tid = threadIdx.x;
  const int wave = tid >> 6;        // gate q: 0=i 1=f 2=g 3=o
  const int lane = tid & 63;
  const int ln = lane & 15, kq = lane >> 4;

  short8 wfrag[16];
  {
    const unsigned short* wb = Whh + (((size_t)((dir<<11) + (wave<<9) + j0 + ln)) << 9) + (kq<<3);
    #pragma unroll
    for (int ks = 0; ks < 16; ++ks)
      wfrag[ks] = *(const short8*)(wb + (ks<<5));
  }
  const int b_ = tid >> 4, jl = tid & 15;
  float c = c0[((size_t)((dir<<4) + b_) << 9) + j0 + jl];

  __shared__ float gsh[4][16][16];
  int* cnt = bar + (dir<<6);   // 256 B apart per dir

  for (int t = 0; t < 512; ++t) {
    // prefetch Xg for this step (independent of barrier/h state)
    const size_t xr = (((size_t)((t<<4) + b_)) << 12) + (dir<<11) + j0 + jl;
    float xg0 = b2f(Xg[xr]);
    float xg1 = b2f(Xg[xr + 512]);
    float xg2 = b2f(Xg[xr + 1024]);
    float xg3 = b2f(Xg[xr + 1536]);

    const unsigned short* hb = Hst + ((((t&1)<<1) + dir)<<13) + (ln<<9) + (kq<<3);
    f32x4 acc0 = {0.f,0.f,0.f,0.f}, acc1 = {0.f,0.f,0.f,0.f};
    #pragma unroll
    for (int ks = 0; ks < 16; ks += 2) {
      short8 a0 = *(const short8*)(hb + (ks<<5));
      short8 a1 = *(const short8*)(hb + ((ks+1)<<5));
      acc0 = __builtin_amdgcn_mfma_f32_16x16x32_bf16(a0, wfrag[ks],   acc0, 0, 0, 0);
      acc1 = __builtin_amdgcn_mfma_f32_16x16x32_bf16(a1, wfrag[ks+1], acc1, 0, 0, 0);
    }
    f32x4 acc = acc0 + acc1;
    #pragma unroll
    for (int r = 0; r < 4; ++r)
      gsh[wave][(kq<<2)+r][ln] = acc[r];
    __syncthreads();

    float gi = gsh[0][b_][jl] + xg0;
    float gf = gsh[1][b_][jl] + xg1;
    float gg = gsh[2][b_][jl] + xg2;
    float go = gsh[3][b_][jl] + xg3;
    float ii = sigm(gi), ff = sigm(gf);
    float g2 = tanhfast(gg), oo = sigm(go);
    c = ff*c + ii*g2;
    float h = oo * tanhfast(c);
    unsigned short h16 = f2b(h);
    Hst[(((((t+1)&1)<<1) + dir)<<13) + (b_<<9) + j0 + jl] = h16;
    size_t crow = (((size_t)((t<<4) + b_)) << 10) + (dir<<9) + j0 + jl;
    Hcat[crow] = h16;
    if (HcatF) HcatF[crow] = h;

    // per-dir grid barrier (32 blocks), monotonic counter
    __syncthreads();   // waits vmcnt(0): all this block's stores have left the CU
    if (tid == 0) {
      const int target = (t + 1) << 5;
      __hip_atomic_fetch_add(cnt, 1, __ATOMIC_ACQ_REL, __HIP_MEMORY_SCOPE_AGENT);
      while (__hip_atomic_load(cnt, __ATOMIC_RELAXED, __HIP_MEMORY_SCOPE_AGENT) < target)
        __builtin_amdgcn_s_sleep(1);
      __builtin_amdgcn_fence(__ATOMIC_ACQUIRE, "agent");
    }
    __syncthreads();
  }
}

// ---------------- softmax over masked scores -> bf16 attention ----------------
__global__ __launch_bounds__(256) void k_softmax(const float* __restrict__ score, const int* __restrict__ tlen,
                                                 unsigned short* __restrict__ att){
  int row = (blockIdx.x<<2) + (threadIdx.x>>6);   // row = b*512 + t
  int lane = threadIdx.x & 63;
  int b = row >> 9;
  int len = tlen[b];
  const float* sr = score + ((size_t)row<<9);
  float v[8]; float m = -3.0e38f;
  #pragma unroll
  for (int i = 0; i < 8; ++i) {
    int s = (i<<6) + lane;
    float x = sr[s];
    v[i] = (s < len) ? x : -1.0e30f;
    m = fmaxf(m, v[i]);
  }
  #pragma unroll
  for (int off = 32; off; off >>= 1) m = fmaxf(m, __shfl_xor(m, off));
  float sum = 0.f; float p[8];
  #pragma unroll
  for (int i = 0; i < 8; ++i) { p[i] = __expf(v[i] - m); sum += p[i]; }
  #pragma unroll
  for (int off = 32; off; off >>= 1) sum += __shfl_xor(sum, off);
  float inv = 1.0f / sum;
  unsigned short* ar = att + ((size_t)row<<9);
  #pragma unroll
  for (int i = 0; i < 8; ++i) ar[(i<<6) + lane] = f2b(p[i]*inv);
}

// ---------------- host ----------------
extern "C" void kernel_launch(void* const* d_in, const int* in_sizes, int n_in,
                              void* d_out, int out_size, void* d_ws, size_t ws_size,
                              hipStream_t stream) {
  (void)in_sizes; (void)n_in; (void)out_size; (void)ws_size;
  const int*   trg  = (const int*)d_in[0];
  const int*   tlen = (const int*)d_in[1];
  const float* enc  = (const float*)d_in[2];
  const float* h0   = (const float*)d_in[3];
  const float* c0   = (const float*)d_in[4];
  const float* emb  = (const float*)d_in[5];
  const float* wih0 = (const float*)d_in[6];
  const float* wih1 = (const float*)d_in[7];
  const float* whh  = (const float*)d_in[8];
  const float* bih  = (const float*)d_in[9];
  const float* bhh  = (const float*)d_in[10];
  const float* watt = (const float*)d_in[11];
  const float* batt = (const float*)d_in[12];
  const float* wfc  = (const float*)d_in[13];
  const float* bfc  = (const float*)d_in[14];
  float* out = (float*)d_out;

  char* ws = (char*)d_ws;
  size_t off = 0;
  auto alloc = [&](size_t bytes)->char* {
    char* p = ws + off; off += (bytes + 255) & ~(size_t)255; return p;
  };
  int*            BAR   = (int*)           alloc(2048);
  unsigned short* XEMB  = (unsigned short*)alloc(8192ll*512*2);
  unsigned short* WI0B  = (unsigned short*)alloc(4096ll*512*2);
  unsigned short* WI1B  = (unsigned short*)alloc(4096ll*1024*2);
  unsigned short* WHHB  = (unsigned short*)alloc(2ll*4096*512*2);
  unsigned short* WFCB  = (unsigned short*)alloc(1000ll*1024*2);
  unsigned short* WATTB = (unsigned short*)alloc(512ll*512*2);
  unsigned short* ENCB  = (unsigned short*)alloc(8192ll*512*2);
  unsigned short* ENCT  = (unsigned short*)alloc(8192ll*512*2);
  float*          BSUM  = (float*)         alloc(8192*4);
  unsigned short* HST0  = (unsigned short*)alloc(32768*2);
  unsigned short* HST1  = (unsigned short*)alloc(32768*2);
  unsigned short* XG    = (unsigned short*)alloc(8192ll*4096*2);
  unsigned short* HCAT  = (unsigned short*)alloc(8192ll*1024*2);
  float*          HCATF = (float*)         alloc(8192ll*1024*4);
  float*          SCORE = (float*)         alloc(8192ll*512*4);   // also used as ENCP f32 staging
  unsigned short* ENCPH = (unsigned short*)alloc(8192ll*512*2);
  unsigned short* ENCPL = (unsigned short*)alloc(8192ll*512*2);
  unsigned short* DECH  = (unsigned short*)alloc(8192ll*512*2);
  unsigned short* DECL  = (unsigned short*)alloc(8192ll*512*2);
  unsigned short* ATT   = (unsigned short*)alloc(8192ll*512*2);
  unsigned short* DCTX  = (unsigned short*)alloc(8192ll*1024*2);

  auto cdiv = [](long a, long b){ return (int)((a + b - 1) / b); };

  // ---- prep ----
  k_cast<<<cdiv(2097152,256),256,0,stream>>>(wih0, WI0B, 2097152);
  k_cast<<<cdiv(4194304,256),256,0,stream>>>(wih1, WI1B, 4194304);
  k_cast<<<cdiv(4194304,256),256,0,stream>>>(whh,  WHHB, 4194304);
  k_cast<<<cdiv(1024000,256),256,0,stream>>>(wfc,  WFCB, 1024000);
  k_cast<<<cdiv(262144,256),256,0,stream>>>(watt, WATTB, 262144);
  k_cast<<<cdiv(4194304,256),256,0,stream>>>(enc,  ENCB, 4194304);
  k_transpose_enc<<<cdiv(4194304,256),256,0,stream>>>(enc, ENCT);
  k_gather<<<cdiv(4194304,256),256,0,stream>>>(trg, emb, XEMB);
  k_bsum<<<cdiv(8192,256),256,0,stream>>>(bih, bhh, BSUM);
  k_init<<<cdiv(32768,256),256,0,stream>>>(h0, HST0, HST1, BAR);

  // ---- enc_proj = enc @ W_att^T + b_att (f32), then hi/lo split ----
  k_gemm<1><<<dim3(64,4,1),256,0,stream>>>(ENCB,512,0, WATTB,512,0, (void*)SCORE,512,0, batt, 8192,512,512, nullptr);
  k_split<<<cdiv(4194304,256),256,0,stream>>>(SCORE, ENCPH, ENCPL, 4194304);

  // ---- X0 = Xemb @ W_ih0^T + (b_ih+b_hh)[0]  -> XG bf16 ----
  k_gemm<0><<<dim3(64,32,1),256,0,stream>>>(XEMB,512,0, WI0B,512,0, (void*)XG,4096,0, BSUM, 8192,4096,512, nullptr);

  // ---- layer 0 recurrence ----
  k_lstm<<<64,256,0,stream>>>(WHHB, XG, c0, HST0, HCAT, nullptr, BAR);

  // ---- X1 = H0cat @ W_ih1^T + (b_ih+b_hh)[1]  -> XG bf16 (reuse) ----
  k_gemm<0><<<dim3(64,32,1),256,0,stream>>>(HCAT,1024,0, WI1B,1024,0, (void*)XG,4096,0, BSUM+4096, 8192,4096,1024, nullptr);

  // ---- layer 1 recurrence (also fp32 H for dec); fresh barrier region ----
  k_lstm<<<64,256,0,stream>>>(WHHB + 2097152, XG, c0 + 16384, HST1, HCAT, HCATF, BAR + 128);

  // ---- dec = hf+hb (fp32) -> DCTX[:, :512] bf16, DECH/DECL split ----
  k_decsplit<<<cdiv(4194304,256),256,0,stream>>>(HCATF, DCTX, DECH, DECL);

  // ---- score[b,t,s] = dec . enc_proj  (hi/lo compensated, batched z=b) ----
  k_gemm<1><<<dim3(4,4,16),256,0,stream>>>(DECH,8192,512, ENCPH,512,262144, (void*)SCORE,512,262144, nullptr, 512,512,512, nullptr);
  k_gemm<3><<<dim3(4,4,16),256,0,stream>>>(DECH,8192,512, ENCPL,512,262144, (void*)SCORE,512,262144, nullptr, 512,512,512, nullptr);
  k_gemm<3><<<dim3(4,4,16),256,0,stream>>>(DECL,8192,512, ENCPH,512,262144, (void*)SCORE,512,262144, nullptr, 512,512,512, nullptr);

  // ---- masked softmax -> ATT bf16 ----
  k_softmax<<<2048,256,0,stream>>>(SCORE, tlen, ATT);

  // ---- ctx[b,t,h] = att @ enc  -> DCTX[:, 512:] bf16 (batched) ----
  k_gemm<0><<<dim3(4,4,16),256,0,stream>>>(ATT,512,262144, ENCT,512,262144, (void*)(DCTX+512),16384,1024, nullptr, 512,512,512, nullptr);

  // ---- out = [dec,ctx] @ W_fc^T + b_fc, masked by trg_len ----
  k_gemm<2><<<dim3(64,8,1),256,0,stream>>>(DCTX,1024,0, WFCB,1024,0, (void*)out,1000,0, bfc, 8192,1000,1024, tlen);
}